// Round 6
// baseline (427.756 us; speedup 1.0000x reference)
//
#include <hip/hip_runtime.h>
#include <hip/hip_bf16.h>
#include <math.h>

// ---- problem constants ----
#define B_ 2
#define L_ 1024
#define HID_ 1536
#define NH_ 24
#define HD_ 64
#define DSSM_ 1536
#define QKV_ 4608

typedef __attribute__((ext_vector_type(8))) short short8;
typedef __attribute__((ext_vector_type(4))) float floatx4;

// async global -> LDS, 16 bytes per lane (global_load_lds_dwordx4)
__device__ __forceinline__ void gload_lds16(const short* g, short* l)
{
    __builtin_amdgcn_global_load_lds(
        (const __attribute__((address_space(1))) void*)g,
        (__attribute__((address_space(3))) void*)l,
        16, 0, 0);
}

__device__ __forceinline__ float bfs2f(short s)
{
    unsigned u = ((unsigned)(unsigned short)s) << 16;
    float f; __builtin_memcpy(&f, &u, 4); return f;
}
__device__ __forceinline__ short f2bfs(float f)
{
    __hip_bfloat16 h = __float2bfloat16(f);
    short s; __builtin_memcpy(&s, &h, 2); return s;
}

// =====================================================================
// fp32 -> bf16 cast (n divisible by 1024)
// =====================================================================
__global__ void cast_kernel(const float* __restrict__ in,
                            __hip_bfloat16* __restrict__ out, int n)
{
    int i = (blockIdx.x * 256 + threadIdx.x) * 4;
    if (i < n) {
        float4 f = *reinterpret_cast<const float4*>(in + i);
        out[i]     = __float2bfloat16(f.x);
        out[i + 1] = __float2bfloat16(f.y);
        out[i + 2] = __float2bfloat16(f.z);
        out[i + 3] = __float2bfloat16(f.w);
    }
}

// =====================================================================
// NT GEMM, LDS-staged (m97 structure) — unchanged
// =====================================================================
template<int OUTMODE>
__global__ __launch_bounds__(256) void gemm_nt(
    const __hip_bfloat16* __restrict__ A,
    const __hip_bfloat16* __restrict__ Bm,
    void* __restrict__ Cv,
    const float* __restrict__ bias,
    int M, int N, int K)
{
    const int lane  = threadIdx.x & 63;
    const int wave  = threadIdx.x >> 6;
    const int col16 = lane & 15;
    const int quad  = lane >> 4;
    const int wr    = wave >> 1;
    const int wc    = wave & 1;
    const int rowblk = blockIdx.y * 128;
    const int colblk = blockIdx.x * 128;

    const short* Ap = reinterpret_cast<const short*>(A);
    const short* Bp = reinterpret_cast<const short*>(Bm);

    __shared__ alignas(16) short As[128 * 32];
    __shared__ alignas(16) short Bs[128 * 32];

    const int srow = lane >> 2;
    const int scol = (lane & 3) * 8;

    floatx4 acc[4][4] = {};

    for (int k0 = 0; k0 < K; k0 += 32) {
#pragma unroll
        for (int s2 = 0; s2 < 2; ++s2) {
            const int seg = wave * 2 + s2;
            gload_lds16(Ap + (size_t)(rowblk + seg * 16 + srow) * K + k0 + scol,
                        &As[seg * 512]);
            gload_lds16(Bp + (size_t)(colblk + seg * 16 + srow) * K + k0 + scol,
                        &Bs[seg * 512]);
        }
        __syncthreads();

        short8 af[4], bf[4];
#pragma unroll
        for (int t = 0; t < 4; ++t) {
            af[t] = *reinterpret_cast<const short8*>(
                &As[(wr * 64 + t * 16 + col16) * 32 + quad * 8]);
            bf[t] = *reinterpret_cast<const short8*>(
                &Bs[(wc * 64 + t * 16 + col16) * 32 + quad * 8]);
        }
#pragma unroll
        for (int mt = 0; mt < 4; ++mt)
#pragma unroll
            for (int nt = 0; nt < 4; ++nt)
                acc[mt][nt] = __builtin_amdgcn_mfma_f32_16x16x32_bf16(
                    af[mt], bf[nt], acc[mt][nt], 0, 0, 0);
        __syncthreads();
    }

    const int row0 = rowblk + wr * 64;
    const int col0 = colblk + wc * 64;
#pragma unroll
    for (int mt = 0; mt < 4; ++mt) {
#pragma unroll
        for (int nt = 0; nt < 4; ++nt) {
#pragma unroll
            for (int r = 0; r < 4; ++r) {
                int row = row0 + mt * 16 + quad * 4 + r;
                int col = col0 + nt * 16 + col16;
                float v = acc[mt][nt][r];
                if (OUTMODE == 1) v += bias[col];
                if (OUTMODE == 2)
                    ((__hip_bfloat16*)Cv)[(size_t)row * N + col] = __float2bfloat16(v);
                else
                    ((float*)Cv)[(size_t)row * N + col] = v;
            }
        }
    }
}

// =====================================================================
// depthwise causal conv (k=2) + SiLU -> q/k/v [B,NH,L,HD] bf16
// =====================================================================
__global__ void conv_silu_kernel(
    const __hip_bfloat16* __restrict__ raw,
    const float* __restrict__ conv_w,
    __hip_bfloat16* __restrict__ q,
    __hip_bfloat16* __restrict__ k,
    __hip_bfloat16* __restrict__ v)
{
    int idx = blockIdx.x * 256 + threadIdx.x;   // over B*L*QKV
    int c  = idx % QKV_;
    int ml = idx / QKV_;
    int l  = ml % L_;

    float cur  = __bfloat162float(raw[idx]);
    float prev = (l > 0) ? __bfloat162float(raw[idx - QKV_]) : 0.f;
    float u = prev * conv_w[c * 2] + cur * conv_w[c * 2 + 1];
    u = fmaxf(u, -80.f);
    float s = u / (1.f + __expf(-u));           // silu

    int part = c / DSSM_;
    int cc   = c % DSSM_;
    int nh   = cc >> 6;
    int d    = cc & 63;
    int b    = ml / L_;
    __hip_bfloat16* dst = (part == 0) ? q : ((part == 1) ? k : v);
    dst[(((size_t)b * NH_ + nh) * L_ + l) * HD_ + d] = __float2bfloat16(s);
}

// =====================================================================
// dt projection (fp32): dt = softplus(x @ w_dt^T + dt_bias); dA = dt*(-exp(a_log))
// =====================================================================
__global__ __launch_bounds__(256) void dtproj_kernel(
    const float* __restrict__ x,
    const float* __restrict__ w_dt,
    const float* __restrict__ dt_bias,
    const float* __restrict__ a_log,
    float* __restrict__ dt,
    float* __restrict__ dA)
{
    int m    = blockIdx.x;
    int b    = m / L_;
    int l    = m % L_;
    int wave = threadIdx.x >> 6;
    int lane = threadIdx.x & 63;
    const float* xr = x + (size_t)m * HID_;

    for (int n = wave; n < NH_; n += 4) {
        float sum = 0.f;
        for (int kk = lane; kk < HID_; kk += 64)
            sum += xr[kk] * w_dt[(size_t)n * HID_ + kk];
#pragma unroll
        for (int off = 32; off; off >>= 1) sum += __shfl_xor(sum, off, 64);
        if (lane == 0) {
            float vdt = sum + dt_bias[n];
            vdt = (vdt > 20.f) ? vdt : log1pf(__expf(vdt));
            float Aval = -__expf(a_log[n]);
            size_t o = ((size_t)b * NH_ + n) * L_ + l;
            dt[o] = vdt;
            dA[o] = vdt * Aval;
        }
    }
}

// =====================================================================
// cumsum over L per (b,nh)
// =====================================================================
__global__ void cumsum_kernel(const float* __restrict__ dA, float* __restrict__ cs)
{
    int bnh  = blockIdx.x;
    int lane = threadIdx.x;
    const float* src = dA + (size_t)bnh * L_;
    float* dst       = cs + (size_t)bnh * L_;

    float loc[16];
    float run = 0.f;
#pragma unroll
    for (int t = 0; t < 16; ++t) { run += src[lane * 16 + t]; loc[t] = run; }
    float tot = run;
    float sc = tot;
#pragma unroll
    for (int off = 1; off < 64; off <<= 1) {
        float o = __shfl_up(sc, off, 64);
        if (lane >= off) sc += o;
    }
    float offset = sc - tot;
#pragma unroll
    for (int t = 0; t < 16; ++t) dst[lane * 16 + t] = loc[t] + offset;
}

// =====================================================================
// V -> Vt transpose with dt folding: vt[b,nh,d,l] = v[b,nh,l,d] * dt[b,nh,l]
// =====================================================================
__global__ __launch_bounds__(256) void vdt_transpose_kernel(
    const __hip_bfloat16* __restrict__ v,   // [B,NH,L,HD]
    const float* __restrict__ dt,           // [B,NH,L]
    __hip_bfloat16* __restrict__ vt)        // [B,NH,HD,L] (dt-scaled)
{
    const int lt0 = blockIdx.x * 64;
    const int bnh = blockIdx.z * NH_ + blockIdx.y;
    const int tid = threadIdx.x;

    __shared__ short T[64][72];

    {
        int row = tid >> 2;
        int cc  = (tid & 3) * 16;
        const short* sp = reinterpret_cast<const short*>(v)
                        + ((size_t)bnh * L_ + lt0 + row) * HD_ + cc;
        float dtr = dt[(size_t)bnh * L_ + lt0 + row];
        short8 a = *reinterpret_cast<const short8*>(sp);
        short8 b = *reinterpret_cast<const short8*>(sp + 8);
#pragma unroll
        for (int j = 0; j < 8; ++j) {
            T[row][cc + j]     = f2bfs(bfs2f(a[j]) * dtr);
            T[row][cc + 8 + j] = f2bfs(bfs2f(b[j]) * dtr);
        }
    }
    __syncthreads();
    {
        int d  = tid >> 2;
        int lc = (tid & 3) * 16;
        short8 o0, o1;
#pragma unroll
        for (int j = 0; j < 8; ++j) {
            o0[j] = T[lc + j][d];
            o1[j] = T[lc + 8 + j][d];
        }
        short* dst = reinterpret_cast<short*>(vt)
                   + ((size_t)bnh * HD_ + d) * L_ + lt0 + lc;
        *reinterpret_cast<short8*>(dst)     = o0;
        *reinterpret_cast<short8*>(dst + 8) = o1;
    }
}

// =====================================================================
// quadratic SSD attention — ONE causal (i-tile, j-tile) 64x64 pair per
// block (4 waves, wave w = 16 i-rows). Partial results accumulated into
// ybuf with fp32 atomics. No j-loop -> short latency chains, 6528 blocks.
// =====================================================================
__global__ __launch_bounds__(256) void attn_kernel(
    const __hip_bfloat16* __restrict__ q,   // [B,NH,L,HD]
    const __hip_bfloat16* __restrict__ k,   // [B,NH,L,HD]
    const __hip_bfloat16* __restrict__ vt,  // [B,NH,HD,L], dt-scaled
    const float* __restrict__ cs,           // [B,NH,L]
    float* __restrict__ y)                  // [B,L,DSSM] fp32 (atomic acc)
{
    // triangular pair index -> (it, jt), jt <= it
    int idx = blockIdx.x;
    int it = (int)((sqrtf(8.f * idx + 1.f) - 1.f) * 0.5f);
    if (it * (it + 1) / 2 > idx) --it;
    if ((it + 1) * (it + 2) / 2 <= idx) ++it;
    const int jt = idx - it * (it + 1) / 2;

    const int nh   = blockIdx.y;
    const int b    = blockIdx.z;
    const int tid  = threadIdx.x;
    const int lane = tid & 63;
    const int wave = tid >> 6;
    const int col  = lane & 15;
    const int quad = lane >> 4;
    const int bnh  = b * NH_ + nh;
    const int iw0  = it * 64 + wave * 16;   // this wave's 16 i-rows
    const int j0   = jt * 64;

    const short* qp  = reinterpret_cast<const short*>(q);
    const short* kp  = reinterpret_cast<const short*>(k);
    const short* vtp = reinterpret_cast<const short*>(vt);

    __shared__ alignas(16) short Ks[4096];        // [2][64][32] (HD halves)
    __shared__ alignas(16) short Ps[4 * 16 * 72]; // per-wave 16x72 P tile

    // stage K tile rows j0..j0+63
    {
        const short* gk = kp + ((size_t)bnh * L_ + j0 + wave * 16 + (lane >> 2)) * HD_
                        + (lane & 3) * 8;
        gload_lds16(gk,      &Ks[wave * 512 + lane * 8]);
        gload_lds16(gk + 32, &Ks[2048 + wave * 512 + lane * 8]);
    }

    // Q fragments (A-layout)
    const short* qrow = qp + ((size_t)bnh * L_ + iw0 + col) * HD_;
    short8 aq0 = *reinterpret_cast<const short8*>(qrow + quad * 8);
    short8 aq1 = *reinterpret_cast<const short8*>(qrow + 32 + quad * 8);

    float csr[4];
#pragma unroll
    for (int r = 0; r < 4; ++r)
        csr[r] = cs[(size_t)bnh * L_ + iw0 + quad * 4 + r];

    __syncthreads();

    // ---- QK^T + decay -> Ps ----
#pragma unroll
    for (int s = 0; s < 4; ++s) {
        int jsub = j0 + s * 16;
        if (jsub <= iw0 + 15) {
            short8 bk0 = *reinterpret_cast<const short8*>(
                &Ks[(s * 16 + col) * 32 + quad * 8]);
            short8 bk1 = *reinterpret_cast<const short8*>(
                &Ks[2048 + (s * 16 + col) * 32 + quad * 8]);
            floatx4 sc = {};
            sc = __builtin_amdgcn_mfma_f32_16x16x32_bf16(aq0, bk0, sc, 0, 0, 0);
            sc = __builtin_amdgcn_mfma_f32_16x16x32_bf16(aq1, bk1, sc, 0, 0, 0);
            int j = jsub + col;
            float csj = cs[(size_t)bnh * L_ + j];
#pragma unroll
            for (int r = 0; r < 4; ++r) {
                int i = iw0 + quad * 4 + r;
                float e = (j <= i) ? __expf(csr[r] - csj) : 0.f;
                Ps[wave * 1152 + (quad * 4 + r) * 72 + s * 16 + col] =
                    f2bfs(sc[r] * e);
            }
        } else if (j0 + (s >> 1) * 32 <= iw0 + 15) {
#pragma unroll
            for (int r = 0; r < 4; ++r)
                Ps[wave * 1152 + (quad * 4 + r) * 72 + s * 16 + col] = 0;
        }
    }

    // ---- PV: accO = P @ Vt ----
    floatx4 accO[4] = {};
#pragma unroll
    for (int c = 0; c < 2; ++c) {
        if (j0 + c * 32 > iw0 + 15) continue;
        short8 pa = *reinterpret_cast<const short8*>(
            &Ps[wave * 1152 + col * 72 + c * 32 + quad * 8]);
#pragma unroll
        for (int nt = 0; nt < 4; ++nt) {
            short8 bv = *reinterpret_cast<const short8*>(
                vtp + ((size_t)bnh * HD_ + nt * 16 + col) * L_
                    + j0 + c * 32 + quad * 8);
            accO[nt] = __builtin_amdgcn_mfma_f32_16x16x32_bf16(pa, bv, accO[nt], 0, 0, 0);
        }
    }

    // ---- atomic accumulate into y [B,L,DSSM] ----
#pragma unroll
    for (int nt = 0; nt < 4; ++nt) {
#pragma unroll
        for (int r = 0; r < 4; ++r) {
            int i  = iw0 + quad * 4 + r;
            int dv = nt * 16 + col;
            atomicAdd(&y[((size_t)b * L_ + i) * DSSM_ + nh * HD_ + dv], accO[nt][r]);
        }
    }
}

// =====================================================================
// gate: (y + v*D) * silu(z), then RMSNorm * rms_w  -> bf16
// =====================================================================
__global__ __launch_bounds__(256) void gate_rms_kernel(
    const float* __restrict__ y,    // [B,L,DSSM] (attention partial sums)
    const float* __restrict__ z,
    const __hip_bfloat16* __restrict__ v,   // [B,NH,L,HD]
    const float* __restrict__ Dm,           // [NH,HD]
    const float* __restrict__ rms_w,
    __hip_bfloat16* __restrict__ yn)
{
    int m   = blockIdx.x;           // b*L + l
    int b   = m / L_;
    int l   = m % L_;
    int tid = threadIdx.x;
    const float* yr = y + (size_t)m * DSSM_;
    const float* zr = z + (size_t)m * DSSM_;

    float g[6];
    float ss = 0.f;
#pragma unroll
    for (int t = 0; t < 6; ++t) {
        int c = tid + t * 256;
        int nh = c >> 6, d = c & 63;
        float vi = __bfloat162float(v[(((size_t)b * NH_ + nh) * L_ + l) * HD_ + d]);
        float yv = yr[c] + vi * Dm[c];
        float zv = fmaxf(zr[c], -80.f);
        float gv = yv * (zv / (1.f + __expf(-zv)));
        g[t] = gv;
        ss += gv * gv;
    }
#pragma unroll
    for (int off = 32; off; off >>= 1) ss += __shfl_xor(ss, off, 64);
    __shared__ float red[4];
    if ((tid & 63) == 0) red[tid >> 6] = ss;
    __syncthreads();
    ss = red[0] + red[1] + red[2] + red[3];
    float r = rsqrtf(ss / (float)DSSM_ + 1e-6f);
#pragma unroll
    for (int t = 0; t < 6; ++t) {
        int c = tid + t * 256;
        yn[(size_t)m * DSSM_ + c] = __float2bfloat16(g[t] * r * rms_w[c]);
    }
}

// =====================================================================
extern "C" void kernel_launch(void* const* d_in, const int* in_sizes, int n_in,
                              void* d_out, int out_size, void* d_ws, size_t ws_size,
                              hipStream_t stream)
{
    const float* x       = (const float*)d_in[0];
    const float* w_qkv   = (const float*)d_in[1];
    const float* conv_w  = (const float*)d_in[2];
    const float* w_dt    = (const float*)d_in[3];
    const float* dt_bias = (const float*)d_in[4];
    const float* a_log   = (const float*)d_in[5];
    const float* Dm      = (const float*)d_in[6];
    const float* w_z     = (const float*)d_in[7];
    const float* b_z     = (const float*)d_in[8];
    const float* rms_w   = (const float*)d_in[9];
    const float* w_o     = (const float*)d_in[10];
    float* out = (float*)d_out;

    char* ws = (char*)d_ws;
    const int M = B_ * L_;                       // 2048

    // ---- workspace layout (bytes), total ~80.8 MB ----
    __hip_bfloat16* xb    = (__hip_bfloat16*)(ws);                  //  6,291,456
    __hip_bfloat16* wqkvb = (__hip_bfloat16*)(ws + 6291456);        // 14,155,776
    __hip_bfloat16* wzb   = (__hip_bfloat16*)(ws + 20447232);       //  4,718,592
    __hip_bfloat16* wob   = (__hip_bfloat16*)(ws + 25165824);       //  4,718,592
    __hip_bfloat16* qkvb  = (__hip_bfloat16*)(ws + 29884416);       // 18,874,368
    __hip_bfloat16* vtb   = (__hip_bfloat16*)(ws + 29884416);       // alias (post-conv)
    float*          zbuf  = (float*)(ws + 29884416);                // alias (post-attn)
    __hip_bfloat16* yn    = (__hip_bfloat16*)(ws + 42467328);
    __hip_bfloat16* qb    = (__hip_bfloat16*)(ws + 48758784);
    __hip_bfloat16* kb    = (__hip_bfloat16*)(ws + 55050240);
    __hip_bfloat16* vb    = (__hip_bfloat16*)(ws + 61341696);
    float* dt   = (float*)(ws + 67633152);
    float* dA   = (float*)(ws + 67829760);
    float* cs   = (float*)(ws + 68026368);
    float* ybuf = (float*)(ws + 68222976);                          // -> 80,805,888

    // 0) casts
    cast_kernel<<<(M * HID_) / 1024, 256, 0, stream>>>(x, xb, M * HID_);
    cast_kernel<<<(QKV_ * HID_) / 1024, 256, 0, stream>>>(w_qkv, wqkvb, QKV_ * HID_);
    cast_kernel<<<(DSSM_ * HID_) / 1024, 256, 0, stream>>>(w_z, wzb, DSSM_ * HID_);
    cast_kernel<<<(HID_ * DSSM_) / 1024, 256, 0, stream>>>(w_o, wob, HID_ * DSSM_);

    // zero attention accumulator (atomic target)
    hipMemsetAsync(ybuf, 0, (size_t)M * DSSM_ * 4, stream);

    // 1) qkv = x @ w_qkv^T
    gemm_nt<2><<<dim3(QKV_ / 128, M / 128), 256, 0, stream>>>(
        xb, wqkvb, (void*)qkvb, nullptr, M, QKV_, HID_);

    // 2) conv + silu -> q,k,v
    conv_silu_kernel<<<(B_ * L_ * QKV_) / 256, 256, 0, stream>>>(
        qkvb, conv_w, qb, kb, vb);

    // 3) dt / dA
    dtproj_kernel<<<M, 256, 0, stream>>>(x, w_dt, dt_bias, a_log, dt, dA);

    // 4) cs = cumsum(dA)
    cumsum_kernel<<<B_ * NH_, 64, 0, stream>>>(dA, cs);

    // 5a) vt = transpose(v) * dt   (qkvb dead; vtb aliases its slot)
    vdt_transpose_kernel<<<dim3(L_ / 64, NH_, B_), 256, 0, stream>>>(vb, dt, vtb);

    // 5b) attention: one causal 64x64 tile-pair per block, atomics into ybuf
    attn_kernel<<<dim3(136, NH_, B_), 256, 0, stream>>>(
        qb, kb, vtb, cs, ybuf);

    // 6) z = x @ w_z^T + b_z   (vtb dead; zbuf aliases)
    gemm_nt<1><<<dim3(DSSM_ / 128, M / 128), 256, 0, stream>>>(
        xb, wzb, (void*)zbuf, b_z, M, DSSM_, HID_);

    // 7) gate (+ v*D skip) + RMSNorm -> yn
    gate_rms_kernel<<<M, 256, 0, stream>>>(ybuf, zbuf, vb, Dm, rms_w, yn);

    // 8) out = yn @ w_o^T
    gemm_nt<0><<<dim3(HID_ / 128, M / 128), 256, 0, stream>>>(
        yn, wob, (void*)out, nullptr, M, HID_, DSSM_);
}

// Round 7
// 396.377 us; speedup vs baseline: 1.0792x; 1.0792x over previous
//
#include <hip/hip_runtime.h>
#include <hip/hip_bf16.h>
#include <math.h>

// ---- problem constants ----
#define B_ 2
#define L_ 1024
#define HID_ 1536
#define NH_ 24
#define HD_ 64
#define DSSM_ 1536
#define QKV_ 4608

typedef __attribute__((ext_vector_type(8))) short short8;
typedef __attribute__((ext_vector_type(4))) float floatx4;

// async global -> LDS, 16 bytes per lane (global_load_lds_dwordx4)
__device__ __forceinline__ void gload_lds16(const short* g, short* l)
{
    __builtin_amdgcn_global_load_lds(
        (const __attribute__((address_space(1))) void*)g,
        (__attribute__((address_space(3))) void*)l,
        16, 0, 0);
}

__device__ __forceinline__ float bfs2f(short s)
{
    unsigned u = ((unsigned)(unsigned short)s) << 16;
    float f; __builtin_memcpy(&f, &u, 4); return f;
}
__device__ __forceinline__ short f2bfs(float f)
{
    __hip_bfloat16 h = __float2bfloat16(f);
    short s; __builtin_memcpy(&s, &h, 2); return s;
}

// (it, slice) lookup for the 30 slice-blocks per (b,nh):
// it 0..5 -> 1 slice; 6..11 -> 2; 12..15 -> 3  (slice = 6 j-tiles)
__device__ const int kIt[30] = {0,1,2,3,4,5, 6,6, 7,7, 8,8, 9,9, 10,10, 11,11,
                                12,12,12, 13,13,13, 14,14,14, 15,15,15};
__device__ const int kS[30]  = {0,0,0,0,0,0, 0,1, 0,1, 0,1, 0,1, 0,1, 0,1,
                                0,1,2, 0,1,2, 0,1,2, 0,1,2};

// =====================================================================
// fp32 -> bf16 cast (n divisible by 1024)
// =====================================================================
__global__ void cast_kernel(const float* __restrict__ in,
                            __hip_bfloat16* __restrict__ out, int n)
{
    int i = (blockIdx.x * 256 + threadIdx.x) * 4;
    if (i < n) {
        float4 f = *reinterpret_cast<const float4*>(in + i);
        out[i]     = __float2bfloat16(f.x);
        out[i + 1] = __float2bfloat16(f.y);
        out[i + 2] = __float2bfloat16(f.z);
        out[i + 3] = __float2bfloat16(f.w);
    }
}

// =====================================================================
// NT GEMM, LDS-staged (m97 structure) — unchanged
// =====================================================================
template<int OUTMODE>
__global__ __launch_bounds__(256) void gemm_nt(
    const __hip_bfloat16* __restrict__ A,
    const __hip_bfloat16* __restrict__ Bm,
    void* __restrict__ Cv,
    const float* __restrict__ bias,
    int M, int N, int K)
{
    const int lane  = threadIdx.x & 63;
    const int wave  = threadIdx.x >> 6;
    const int col16 = lane & 15;
    const int quad  = lane >> 4;
    const int wr    = wave >> 1;
    const int wc    = wave & 1;
    const int rowblk = blockIdx.y * 128;
    const int colblk = blockIdx.x * 128;

    const short* Ap = reinterpret_cast<const short*>(A);
    const short* Bp = reinterpret_cast<const short*>(Bm);

    __shared__ alignas(16) short As[128 * 32];
    __shared__ alignas(16) short Bs[128 * 32];

    const int srow = lane >> 2;
    const int scol = (lane & 3) * 8;

    floatx4 acc[4][4] = {};

    for (int k0 = 0; k0 < K; k0 += 32) {
#pragma unroll
        for (int s2 = 0; s2 < 2; ++s2) {
            const int seg = wave * 2 + s2;
            gload_lds16(Ap + (size_t)(rowblk + seg * 16 + srow) * K + k0 + scol,
                        &As[seg * 512]);
            gload_lds16(Bp + (size_t)(colblk + seg * 16 + srow) * K + k0 + scol,
                        &Bs[seg * 512]);
        }
        __syncthreads();

        short8 af[4], bf[4];
#pragma unroll
        for (int t = 0; t < 4; ++t) {
            af[t] = *reinterpret_cast<const short8*>(
                &As[(wr * 64 + t * 16 + col16) * 32 + quad * 8]);
            bf[t] = *reinterpret_cast<const short8*>(
                &Bs[(wc * 64 + t * 16 + col16) * 32 + quad * 8]);
        }
#pragma unroll
        for (int mt = 0; mt < 4; ++mt)
#pragma unroll
            for (int nt = 0; nt < 4; ++nt)
                acc[mt][nt] = __builtin_amdgcn_mfma_f32_16x16x32_bf16(
                    af[mt], bf[nt], acc[mt][nt], 0, 0, 0);
        __syncthreads();
    }

    const int row0 = rowblk + wr * 64;
    const int col0 = colblk + wc * 64;
#pragma unroll
    for (int mt = 0; mt < 4; ++mt) {
#pragma unroll
        for (int nt = 0; nt < 4; ++nt) {
#pragma unroll
            for (int r = 0; r < 4; ++r) {
                int row = row0 + mt * 16 + quad * 4 + r;
                int col = col0 + nt * 16 + col16;
                float v = acc[mt][nt][r];
                if (OUTMODE == 1) v += bias[col];
                if (OUTMODE == 2)
                    ((__hip_bfloat16*)Cv)[(size_t)row * N + col] = __float2bfloat16(v);
                else
                    ((float*)Cv)[(size_t)row * N + col] = v;
            }
        }
    }
}

// =====================================================================
// depthwise causal conv (k=2) + SiLU -> q/k/v [B,NH,L,HD] bf16
// =====================================================================
__global__ void conv_silu_kernel(
    const __hip_bfloat16* __restrict__ raw,
    const float* __restrict__ conv_w,
    __hip_bfloat16* __restrict__ q,
    __hip_bfloat16* __restrict__ k,
    __hip_bfloat16* __restrict__ v)
{
    int idx = blockIdx.x * 256 + threadIdx.x;   // over B*L*QKV
    int c  = idx % QKV_;
    int ml = idx / QKV_;
    int l  = ml % L_;

    float cur  = __bfloat162float(raw[idx]);
    float prev = (l > 0) ? __bfloat162float(raw[idx - QKV_]) : 0.f;
    float u = prev * conv_w[c * 2] + cur * conv_w[c * 2 + 1];
    u = fmaxf(u, -80.f);
    float s = u / (1.f + __expf(-u));           // silu

    int part = c / DSSM_;
    int cc   = c % DSSM_;
    int nh   = cc >> 6;
    int d    = cc & 63;
    int b    = ml / L_;
    __hip_bfloat16* dst = (part == 0) ? q : ((part == 1) ? k : v);
    dst[(((size_t)b * NH_ + nh) * L_ + l) * HD_ + d] = __float2bfloat16(s);
}

// =====================================================================
// dt projection (fp32): dt = softplus(x @ w_dt^T + dt_bias); dA = dt*(-exp(a_log))
// =====================================================================
__global__ __launch_bounds__(256) void dtproj_kernel(
    const float* __restrict__ x,
    const float* __restrict__ w_dt,
    const float* __restrict__ dt_bias,
    const float* __restrict__ a_log,
    float* __restrict__ dt,
    float* __restrict__ dA)
{
    int m    = blockIdx.x;
    int b    = m / L_;
    int l    = m % L_;
    int wave = threadIdx.x >> 6;
    int lane = threadIdx.x & 63;
    const float* xr = x + (size_t)m * HID_;

    for (int n = wave; n < NH_; n += 4) {
        float sum = 0.f;
        for (int kk = lane; kk < HID_; kk += 64)
            sum += xr[kk] * w_dt[(size_t)n * HID_ + kk];
#pragma unroll
        for (int off = 32; off; off >>= 1) sum += __shfl_xor(sum, off, 64);
        if (lane == 0) {
            float vdt = sum + dt_bias[n];
            vdt = (vdt > 20.f) ? vdt : log1pf(__expf(vdt));
            float Aval = -__expf(a_log[n]);
            size_t o = ((size_t)b * NH_ + n) * L_ + l;
            dt[o] = vdt;
            dA[o] = vdt * Aval;
        }
    }
}

// =====================================================================
// cumsum over L per (b,nh)
// =====================================================================
__global__ void cumsum_kernel(const float* __restrict__ dA, float* __restrict__ cs)
{
    int bnh  = blockIdx.x;
    int lane = threadIdx.x;
    const float* src = dA + (size_t)bnh * L_;
    float* dst       = cs + (size_t)bnh * L_;

    float loc[16];
    float run = 0.f;
#pragma unroll
    for (int t = 0; t < 16; ++t) { run += src[lane * 16 + t]; loc[t] = run; }
    float tot = run;
    float sc = tot;
#pragma unroll
    for (int off = 1; off < 64; off <<= 1) {
        float o = __shfl_up(sc, off, 64);
        if (lane >= off) sc += o;
    }
    float offset = sc - tot;
#pragma unroll
    for (int t = 0; t < 16; ++t) dst[lane * 16 + t] = loc[t] + offset;
}

// =====================================================================
// V -> Vt transpose with dt folding: vt[b,nh,d,l] = v[b,nh,l,d] * dt[b,nh,l]
// =====================================================================
__global__ __launch_bounds__(256) void vdt_transpose_kernel(
    const __hip_bfloat16* __restrict__ v,   // [B,NH,L,HD]
    const float* __restrict__ dt,           // [B,NH,L]
    __hip_bfloat16* __restrict__ vt)        // [B,NH,HD,L] (dt-scaled)
{
    const int lt0 = blockIdx.x * 64;
    const int bnh = blockIdx.z * NH_ + blockIdx.y;
    const int tid = threadIdx.x;

    __shared__ short T[64][72];

    {
        int row = tid >> 2;
        int cc  = (tid & 3) * 16;
        const short* sp = reinterpret_cast<const short*>(v)
                        + ((size_t)bnh * L_ + lt0 + row) * HD_ + cc;
        float dtr = dt[(size_t)bnh * L_ + lt0 + row];
        short8 a = *reinterpret_cast<const short8*>(sp);
        short8 b = *reinterpret_cast<const short8*>(sp + 8);
#pragma unroll
        for (int j = 0; j < 8; ++j) {
            T[row][cc + j]     = f2bfs(bfs2f(a[j]) * dtr);
            T[row][cc + 8 + j] = f2bfs(bfs2f(b[j]) * dtr);
        }
    }
    __syncthreads();
    {
        int d  = tid >> 2;
        int lc = (tid & 3) * 16;
        short8 o0, o1;
#pragma unroll
        for (int j = 0; j < 8; ++j) {
            o0[j] = T[lc + j][d];
            o1[j] = T[lc + 8 + j][d];
        }
        short* dst = reinterpret_cast<short*>(vt)
                   + ((size_t)bnh * HD_ + d) * L_ + lt0 + lc;
        *reinterpret_cast<short8*>(dst)     = o0;
        *reinterpret_cast<short8*>(dst + 8) = o1;
    }
}

// =====================================================================
// quadratic SSD attention — one (i-tile, j-slice) per block.
// Slice = up to 6 j-tiles of 64. Each block owns its 64x64 output tile in
// partial buffer p[slice] -> plain stores, NO atomics. 1440 blocks.
// =====================================================================
__global__ __launch_bounds__(256) void attn_kernel(
    const __hip_bfloat16* __restrict__ q,   // [B,NH,L,HD]
    const __hip_bfloat16* __restrict__ k,   // [B,NH,L,HD]
    const __hip_bfloat16* __restrict__ vt,  // [B,NH,HD,L], dt-scaled
    const float* __restrict__ cs,           // [B,NH,L]
    float* __restrict__ p0,                 // [B,L,DSSM] partials
    float* __restrict__ p1,
    float* __restrict__ p2)
{
    const int pidx = blockIdx.x;            // 0..29
    const int it   = kIt[pidx];
    const int sl   = kS[pidx];
    const int nh   = blockIdx.y;
    const int b    = blockIdx.z;
    const int tid  = threadIdx.x;
    const int lane = tid & 63;
    const int wave = tid >> 6;
    const int col  = lane & 15;
    const int quad = lane >> 4;
    const int bnh  = b * NH_ + nh;
    const int iw0  = it * 64 + wave * 16;   // this wave's 16 i-rows

    float* pout = (sl == 0) ? p0 : ((sl == 1) ? p1 : p2);

    const short* qp  = reinterpret_cast<const short*>(q);
    const short* kp  = reinterpret_cast<const short*>(k);
    const short* vtp = reinterpret_cast<const short*>(vt);

    __shared__ alignas(16) short Ks[4096];        // [2][64][32] (HD halves)
    __shared__ alignas(16) short Ps[4 * 16 * 72]; // per-wave 16x72 P tile

    // Q fragments (A-layout)
    const short* qrow = qp + ((size_t)bnh * L_ + iw0 + col) * HD_;
    short8 aq0 = *reinterpret_cast<const short8*>(qrow + quad * 8);
    short8 aq1 = *reinterpret_cast<const short8*>(qrow + 32 + quad * 8);

    float csr[4];
#pragma unroll
    for (int r = 0; r < 4; ++r)
        csr[r] = cs[(size_t)bnh * L_ + iw0 + quad * 4 + r];

    floatx4 accO[4] = {};

    const int jt_end = min(sl * 6 + 5, it);
    for (int jt = sl * 6; jt <= jt_end; ++jt) {
        const int j0 = jt * 64;
        // stage K tile rows j0..j0+63
        {
            const short* gk = kp + ((size_t)bnh * L_ + j0 + wave * 16 + (lane >> 2)) * HD_
                            + (lane & 3) * 8;
            gload_lds16(gk,      &Ks[wave * 512 + lane * 8]);
            gload_lds16(gk + 32, &Ks[2048 + wave * 512 + lane * 8]);
        }
        __syncthreads();

        // ---- QK^T + decay -> Ps ----
#pragma unroll
        for (int s = 0; s < 4; ++s) {
            int jsub = j0 + s * 16;
            if (jsub <= iw0 + 15) {
                short8 bk0 = *reinterpret_cast<const short8*>(
                    &Ks[(s * 16 + col) * 32 + quad * 8]);
                short8 bk1 = *reinterpret_cast<const short8*>(
                    &Ks[2048 + (s * 16 + col) * 32 + quad * 8]);
                floatx4 sc = {};
                sc = __builtin_amdgcn_mfma_f32_16x16x32_bf16(aq0, bk0, sc, 0, 0, 0);
                sc = __builtin_amdgcn_mfma_f32_16x16x32_bf16(aq1, bk1, sc, 0, 0, 0);
                int j = jsub + col;
                float csj = cs[(size_t)bnh * L_ + j];
#pragma unroll
                for (int r = 0; r < 4; ++r) {
                    int i = iw0 + quad * 4 + r;
                    float e = (j <= i) ? __expf(csr[r] - csj) : 0.f;
                    Ps[wave * 1152 + (quad * 4 + r) * 72 + s * 16 + col] =
                        f2bfs(sc[r] * e);
                }
            } else if (j0 + (s >> 1) * 32 <= iw0 + 15) {
#pragma unroll
                for (int r = 0; r < 4; ++r)
                    Ps[wave * 1152 + (quad * 4 + r) * 72 + s * 16 + col] = 0;
            }
        }

        // ---- PV: accO += P @ Vt ----
#pragma unroll
        for (int c = 0; c < 2; ++c) {
            if (j0 + c * 32 > iw0 + 15) continue;
            short8 pa = *reinterpret_cast<const short8*>(
                &Ps[wave * 1152 + col * 72 + c * 32 + quad * 8]);
#pragma unroll
            for (int nt = 0; nt < 4; ++nt) {
                short8 bv = *reinterpret_cast<const short8*>(
                    vtp + ((size_t)bnh * HD_ + nt * 16 + col) * L_
                        + j0 + c * 32 + quad * 8);
                accO[nt] = __builtin_amdgcn_mfma_f32_16x16x32_bf16(pa, bv, accO[nt], 0, 0, 0);
            }
        }
        __syncthreads();
    }

    // ---- plain store into this slice's partial buffer ----
#pragma unroll
    for (int nt = 0; nt < 4; ++nt) {
#pragma unroll
        for (int r = 0; r < 4; ++r) {
            int i  = iw0 + quad * 4 + r;
            int dv = nt * 16 + col;
            pout[((size_t)b * L_ + i) * DSSM_ + nh * HD_ + dv] = accO[nt][r];
        }
    }
}

// =====================================================================
// gate: (p0+p1+p2 + v*D) * silu(z), then RMSNorm * rms_w  -> bf16
// =====================================================================
__global__ __launch_bounds__(256) void gate_rms_kernel(
    const float* __restrict__ p0,
    const float* __restrict__ p1,
    const float* __restrict__ p2,
    const float* __restrict__ z,
    const __hip_bfloat16* __restrict__ v,   // [B,NH,L,HD]
    const float* __restrict__ Dm,           // [NH,HD]
    const float* __restrict__ rms_w,
    __hip_bfloat16* __restrict__ yn)
{
    int m   = blockIdx.x;           // b*L + l
    int b   = m / L_;
    int l   = m % L_;
    int tid = threadIdx.x;
    size_t base = (size_t)m * DSSM_;

    float g[6];
    float ss = 0.f;
#pragma unroll
    for (int t = 0; t < 6; ++t) {
        int c = tid + t * 256;
        int nh = c >> 6, d = c & 63;
        float vi = __bfloat162float(v[(((size_t)b * NH_ + nh) * L_ + l) * HD_ + d]);
        float yv = p0[base + c] + p1[base + c] + p2[base + c] + vi * Dm[c];
        float zv = fmaxf(z[base + c], -80.f);
        float gv = yv * (zv / (1.f + __expf(-zv)));
        g[t] = gv;
        ss += gv * gv;
    }
#pragma unroll
    for (int off = 32; off; off >>= 1) ss += __shfl_xor(ss, off, 64);
    __shared__ float red[4];
    if ((tid & 63) == 0) red[tid >> 6] = ss;
    __syncthreads();
    ss = red[0] + red[1] + red[2] + red[3];
    float r = rsqrtf(ss / (float)DSSM_ + 1e-6f);
#pragma unroll
    for (int t = 0; t < 6; ++t) {
        int c = tid + t * 256;
        yn[base + c] = __float2bfloat16(g[t] * r * rms_w[c]);
    }
}

// =====================================================================
extern "C" void kernel_launch(void* const* d_in, const int* in_sizes, int n_in,
                              void* d_out, int out_size, void* d_ws, size_t ws_size,
                              hipStream_t stream)
{
    const float* x       = (const float*)d_in[0];
    const float* w_qkv   = (const float*)d_in[1];
    const float* conv_w  = (const float*)d_in[2];
    const float* w_dt    = (const float*)d_in[3];
    const float* dt_bias = (const float*)d_in[4];
    const float* a_log   = (const float*)d_in[5];
    const float* Dm      = (const float*)d_in[6];
    const float* w_z     = (const float*)d_in[7];
    const float* b_z     = (const float*)d_in[8];
    const float* rms_w   = (const float*)d_in[9];
    const float* w_o     = (const float*)d_in[10];
    float* out = (float*)d_out;

    char* ws = (char*)d_ws;
    const int M = B_ * L_;                       // 2048
    const size_t PSZ = (size_t)M * DSSM_ * 4;    // 12,582,912 bytes

    // ---- workspace layout (bytes), total 80,805,888 ----
    __hip_bfloat16* xb    = (__hip_bfloat16*)(ws);                  // 0 .. 6.29M   (casts->step6)
    __hip_bfloat16* wqkvb = (__hip_bfloat16*)(ws + 6291456);        // 6.29 .. 20.45M (dead after step1)
    float*          p1    = (float*)(ws + 6291456);                 //   alias: partial 1
    __hip_bfloat16* wzb   = (__hip_bfloat16*)(ws + 20447232);       // -> step6
    __hip_bfloat16* wob   = (__hip_bfloat16*)(ws + 25165824);       // -> step8
    __hip_bfloat16* qkvb  = (__hip_bfloat16*)(ws + 29884416);       // 29.88 .. 48.76M (dead after step2)
    __hip_bfloat16* vtb   = (__hip_bfloat16*)(ws + 29884416);       //   alias: vt (transpose->attn)
    __hip_bfloat16* yn    = (__hip_bfloat16*)(ws + 29884416);       //   alias: yn (step7->8)
    float*          p2    = (float*)(ws + 36175872);                //   alias: partial 2 (after conv)
    __hip_bfloat16* qb    = (__hip_bfloat16*)(ws + 48758784);       // conv->attn
    __hip_bfloat16* kb    = (__hip_bfloat16*)(ws + 55050240);       // conv->attn
    float*          zbuf  = (float*)(ws + 48758784);                //   alias over qb+kb (step6->7)
    __hip_bfloat16* vb    = (__hip_bfloat16*)(ws + 61341696);       // conv->step7
    float* dt   = (float*)(ws + 67633152);
    float* dA   = (float*)(ws + 67829760);
    float* cs   = (float*)(ws + 68026368);
    float* p0   = (float*)(ws + 68222976);                          // partial 0 -> 80,805,888

    // 0) casts
    cast_kernel<<<(M * HID_) / 1024, 256, 0, stream>>>(x, xb, M * HID_);
    cast_kernel<<<(QKV_ * HID_) / 1024, 256, 0, stream>>>(w_qkv, wqkvb, QKV_ * HID_);
    cast_kernel<<<(DSSM_ * HID_) / 1024, 256, 0, stream>>>(w_z, wzb, DSSM_ * HID_);
    cast_kernel<<<(HID_ * DSSM_) / 1024, 256, 0, stream>>>(w_o, wob, HID_ * DSSM_);

    hipMemsetAsync(p0, 0, PSZ, stream);

    // 1) qkv = x @ w_qkv^T
    gemm_nt<2><<<dim3(QKV_ / 128, M / 128), 256, 0, stream>>>(
        xb, wqkvb, (void*)qkvb, nullptr, M, QKV_, HID_);

    // 2) conv + silu -> q,k,v
    conv_silu_kernel<<<(B_ * L_ * QKV_) / 256, 256, 0, stream>>>(
        qkvb, conv_w, qb, kb, vb);

    // partials 1/2 reuse wqkvb / qkv-tail, both dead now (stream-ordered)
    hipMemsetAsync(p1, 0, PSZ, stream);
    hipMemsetAsync(p2, 0, PSZ, stream);

    // 3) dt / dA
    dtproj_kernel<<<M, 256, 0, stream>>>(x, w_dt, dt_bias, a_log, dt, dA);

    // 4) cs = cumsum(dA)
    cumsum_kernel<<<B_ * NH_, 64, 0, stream>>>(dA, cs);

    // 5a) vt = transpose(v) * dt
    vdt_transpose_kernel<<<dim3(L_ / 64, NH_, B_), 256, 0, stream>>>(vb, dt, vtb);

    // 5b) attention: (i-tile, j-slice) blocks, plain stores into partials
    attn_kernel<<<dim3(30, NH_, B_), 256, 0, stream>>>(
        qb, kb, vtb, cs, p0, p1, p2);

    // 6) z = x @ w_z^T + b_z   (qb/kb dead; zbuf aliases them)
    gemm_nt<1><<<dim3(DSSM_ / 128, M / 128), 256, 0, stream>>>(
        xb, wzb, (void*)zbuf, b_z, M, DSSM_, HID_);

    // 7) gate (p0+p1+p2 + v*D) + RMSNorm -> yn (vt slot)
    gate_rms_kernel<<<M, 256, 0, stream>>>(p0, p1, p2, zbuf, vb, Dm, rms_w, yn);

    // 8) out = yn @ w_o^T
    gemm_nt<0><<<dim3(HID_ / 128, M / 128), 256, 0, stream>>>(
        yn, wob, (void*)out, nullptr, M, HID_, DSSM_);
}

// Round 8
// 369.508 us; speedup vs baseline: 1.1576x; 1.0727x over previous
//
#include <hip/hip_runtime.h>
#include <hip/hip_bf16.h>
#include <math.h>

// ---- problem constants ----
#define B_ 2
#define L_ 1024
#define HID_ 1536
#define NH_ 24
#define HD_ 64
#define DSSM_ 1536
#define QKV_ 4608

typedef __attribute__((ext_vector_type(8))) short short8;
typedef __attribute__((ext_vector_type(4))) float floatx4;

// async global -> LDS, 16 bytes per lane (global_load_lds_dwordx4)
__device__ __forceinline__ void gload_lds16(const short* g, short* l)
{
    __builtin_amdgcn_global_load_lds(
        (const __attribute__((address_space(1))) void*)g,
        (__attribute__((address_space(3))) void*)l,
        16, 0, 0);
}

__device__ __forceinline__ float bfs2f(short s)
{
    unsigned u = ((unsigned)(unsigned short)s) << 16;
    float f; __builtin_memcpy(&f, &u, 4); return f;
}
__device__ __forceinline__ short f2bfs(float f)
{
    __hip_bfloat16 h = __float2bfloat16(f);
    short s; __builtin_memcpy(&s, &h, 2); return s;
}

// (it, slice) lookup for the 30 slice-blocks per (b,nh):
// it 0..5 -> 1 slice; 6..11 -> 2; 12..15 -> 3  (slice = 6 j-tiles)
__device__ const int kIt[30] = {0,1,2,3,4,5, 6,6, 7,7, 8,8, 9,9, 10,10, 11,11,
                                12,12,12, 13,13,13, 14,14,14, 15,15,15};
__device__ const int kS[30]  = {0,0,0,0,0,0, 0,1, 0,1, 0,1, 0,1, 0,1, 0,1,
                                0,1,2, 0,1,2, 0,1,2, 0,1,2};

// =====================================================================
// fp32 -> bf16 cast (n divisible by 1024)
// =====================================================================
__global__ void cast_kernel(const float* __restrict__ in,
                            __hip_bfloat16* __restrict__ out, int n)
{
    int i = (blockIdx.x * 256 + threadIdx.x) * 4;
    if (i < n) {
        float4 f = *reinterpret_cast<const float4*>(in + i);
        out[i]     = __float2bfloat16(f.x);
        out[i + 1] = __float2bfloat16(f.y);
        out[i + 2] = __float2bfloat16(f.z);
        out[i + 3] = __float2bfloat16(f.w);
    }
}

// =====================================================================
// NT GEMM, LDS-staged (m97 structure) — unchanged
// =====================================================================
template<int OUTMODE>
__global__ __launch_bounds__(256) void gemm_nt(
    const __hip_bfloat16* __restrict__ A,
    const __hip_bfloat16* __restrict__ Bm,
    void* __restrict__ Cv,
    const float* __restrict__ bias,
    int M, int N, int K)
{
    const int lane  = threadIdx.x & 63;
    const int wave  = threadIdx.x >> 6;
    const int col16 = lane & 15;
    const int quad  = lane >> 4;
    const int wr    = wave >> 1;
    const int wc    = wave & 1;
    const int rowblk = blockIdx.y * 128;
    const int colblk = blockIdx.x * 128;

    const short* Ap = reinterpret_cast<const short*>(A);
    const short* Bp = reinterpret_cast<const short*>(Bm);

    __shared__ alignas(16) short As[128 * 32];
    __shared__ alignas(16) short Bs[128 * 32];

    const int srow = lane >> 2;
    const int scol = (lane & 3) * 8;

    floatx4 acc[4][4] = {};

    for (int k0 = 0; k0 < K; k0 += 32) {
#pragma unroll
        for (int s2 = 0; s2 < 2; ++s2) {
            const int seg = wave * 2 + s2;
            gload_lds16(Ap + (size_t)(rowblk + seg * 16 + srow) * K + k0 + scol,
                        &As[seg * 512]);
            gload_lds16(Bp + (size_t)(colblk + seg * 16 + srow) * K + k0 + scol,
                        &Bs[seg * 512]);
        }
        __syncthreads();

        short8 af[4], bf[4];
#pragma unroll
        for (int t = 0; t < 4; ++t) {
            af[t] = *reinterpret_cast<const short8*>(
                &As[(wr * 64 + t * 16 + col16) * 32 + quad * 8]);
            bf[t] = *reinterpret_cast<const short8*>(
                &Bs[(wc * 64 + t * 16 + col16) * 32 + quad * 8]);
        }
#pragma unroll
        for (int mt = 0; mt < 4; ++mt)
#pragma unroll
            for (int nt = 0; nt < 4; ++nt)
                acc[mt][nt] = __builtin_amdgcn_mfma_f32_16x16x32_bf16(
                    af[mt], bf[nt], acc[mt][nt], 0, 0, 0);
        __syncthreads();
    }

    const int row0 = rowblk + wr * 64;
    const int col0 = colblk + wc * 64;
#pragma unroll
    for (int mt = 0; mt < 4; ++mt) {
#pragma unroll
        for (int nt = 0; nt < 4; ++nt) {
#pragma unroll
            for (int r = 0; r < 4; ++r) {
                int row = row0 + mt * 16 + quad * 4 + r;
                int col = col0 + nt * 16 + col16;
                float v = acc[mt][nt][r];
                if (OUTMODE == 1) v += bias[col];
                if (OUTMODE == 2)
                    ((__hip_bfloat16*)Cv)[(size_t)row * N + col] = __float2bfloat16(v);
                else
                    ((float*)Cv)[(size_t)row * N + col] = v;
            }
        }
    }
}

// =====================================================================
// depthwise causal conv (k=2) + SiLU -> q/k/v [B,NH,L,HD] bf16
// =====================================================================
__global__ void conv_silu_kernel(
    const __hip_bfloat16* __restrict__ raw,
    const float* __restrict__ conv_w,
    __hip_bfloat16* __restrict__ q,
    __hip_bfloat16* __restrict__ k,
    __hip_bfloat16* __restrict__ v)
{
    int idx = blockIdx.x * 256 + threadIdx.x;   // over B*L*QKV
    int c  = idx % QKV_;
    int ml = idx / QKV_;
    int l  = ml % L_;

    float cur  = __bfloat162float(raw[idx]);
    float prev = (l > 0) ? __bfloat162float(raw[idx - QKV_]) : 0.f;
    float u = prev * conv_w[c * 2] + cur * conv_w[c * 2 + 1];
    u = fmaxf(u, -80.f);
    float s = u / (1.f + __expf(-u));           // silu

    int part = c / DSSM_;
    int cc   = c % DSSM_;
    int nh   = cc >> 6;
    int d    = cc & 63;
    int b    = ml / L_;
    __hip_bfloat16* dst = (part == 0) ? q : ((part == 1) ? k : v);
    dst[(((size_t)b * NH_ + nh) * L_ + l) * HD_ + d] = __float2bfloat16(s);
}

// =====================================================================
// dt projection v2 (fp32, LDS-staged x, register-held fragments):
// 8 rows per block; wave owns 2 rows; lane owns 24 contiguous k-elems.
// dt = softplus(x @ w_dt^T + dt_bias); dA = dt * (-exp(a_log))
// =====================================================================
__global__ __launch_bounds__(256) void dtproj_kernel(
    const float* __restrict__ x,        // [B*L, HID]
    const float* __restrict__ w_dt,     // [NH, HID]
    const float* __restrict__ dt_bias,  // [NH]
    const float* __restrict__ a_log,    // [NH]
    float* __restrict__ dt,             // [B*NH, L]
    float* __restrict__ dA)
{
    const int m0   = blockIdx.x * 8;
    const int tid  = threadIdx.x;
    const int wave = tid >> 6;
    const int lane = tid & 63;

    __shared__ float Xs[8][HID_];

    // stage 8 x rows, coalesced float4
    for (int t = tid; t < 8 * (HID_ / 4); t += 256) {
        int r = t / (HID_ / 4), c = (t % (HID_ / 4)) * 4;
        *reinterpret_cast<float4*>(&Xs[r][c]) =
            *reinterpret_cast<const float4*>(x + (size_t)(m0 + r) * HID_ + c);
    }
    __syncthreads();

    const int r0 = wave * 2;
    float4 xa[2][6];
#pragma unroll
    for (int rr = 0; rr < 2; ++rr)
#pragma unroll
        for (int it = 0; it < 6; ++it)
            xa[rr][it] = *reinterpret_cast<const float4*>(&Xs[r0 + rr][lane * 4 + it * 256]);

    for (int n = 0; n < NH_; ++n) {
        float s0 = 0.f, s1 = 0.f;
#pragma unroll
        for (int it = 0; it < 6; ++it) {
            float4 w = *reinterpret_cast<const float4*>(
                w_dt + (size_t)n * HID_ + lane * 4 + it * 256);
            s0 += xa[0][it].x * w.x + xa[0][it].y * w.y
                + xa[0][it].z * w.z + xa[0][it].w * w.w;
            s1 += xa[1][it].x * w.x + xa[1][it].y * w.y
                + xa[1][it].z * w.z + xa[1][it].w * w.w;
        }
#pragma unroll
        for (int off = 32; off; off >>= 1) {
            s0 += __shfl_xor(s0, off, 64);
            s1 += __shfl_xor(s1, off, 64);
        }
        if (lane == 0) {
            float Aval = -__expf(a_log[n]);
            float bias = dt_bias[n];
#pragma unroll
            for (int rr = 0; rr < 2; ++rr) {
                float vdt = (rr == 0 ? s0 : s1) + bias;
                vdt = (vdt > 20.f) ? vdt : log1pf(__expf(vdt));
                int m = m0 + r0 + rr;
                int b = m / L_, l = m % L_;
                size_t o = ((size_t)b * NH_ + n) * L_ + l;
                dt[o] = vdt;
                dA[o] = vdt * Aval;
            }
        }
    }
}

// =====================================================================
// cumsum over L per (b,nh)
// =====================================================================
__global__ void cumsum_kernel(const float* __restrict__ dA, float* __restrict__ cs)
{
    int bnh  = blockIdx.x;
    int lane = threadIdx.x;
    const float* src = dA + (size_t)bnh * L_;
    float* dst       = cs + (size_t)bnh * L_;

    float loc[16];
    float run = 0.f;
#pragma unroll
    for (int t = 0; t < 16; ++t) { run += src[lane * 16 + t]; loc[t] = run; }
    float tot = run;
    float sc = tot;
#pragma unroll
    for (int off = 1; off < 64; off <<= 1) {
        float o = __shfl_up(sc, off, 64);
        if (lane >= off) sc += o;
    }
    float offset = sc - tot;
#pragma unroll
    for (int t = 0; t < 16; ++t) dst[lane * 16 + t] = loc[t] + offset;
}

// =====================================================================
// V -> Vt transpose with dt folding: vt[b,nh,d,l] = v[b,nh,l,d] * dt[b,nh,l]
// =====================================================================
__global__ __launch_bounds__(256) void vdt_transpose_kernel(
    const __hip_bfloat16* __restrict__ v,   // [B,NH,L,HD]
    const float* __restrict__ dt,           // [B,NH,L]
    __hip_bfloat16* __restrict__ vt)        // [B,NH,HD,L] (dt-scaled)
{
    const int lt0 = blockIdx.x * 64;
    const int bnh = blockIdx.z * NH_ + blockIdx.y;
    const int tid = threadIdx.x;

    __shared__ short T[64][72];

    {
        int row = tid >> 2;
        int cc  = (tid & 3) * 16;
        const short* sp = reinterpret_cast<const short*>(v)
                        + ((size_t)bnh * L_ + lt0 + row) * HD_ + cc;
        float dtr = dt[(size_t)bnh * L_ + lt0 + row];
        short8 a = *reinterpret_cast<const short8*>(sp);
        short8 b = *reinterpret_cast<const short8*>(sp + 8);
#pragma unroll
        for (int j = 0; j < 8; ++j) {
            T[row][cc + j]     = f2bfs(bfs2f(a[j]) * dtr);
            T[row][cc + 8 + j] = f2bfs(bfs2f(b[j]) * dtr);
        }
    }
    __syncthreads();
    {
        int d  = tid >> 2;
        int lc = (tid & 3) * 16;
        short8 o0, o1;
#pragma unroll
        for (int j = 0; j < 8; ++j) {
            o0[j] = T[lc + j][d];
            o1[j] = T[lc + 8 + j][d];
        }
        short* dst = reinterpret_cast<short*>(vt)
                   + ((size_t)bnh * HD_ + d) * L_ + lt0 + lc;
        *reinterpret_cast<short8*>(dst)     = o0;
        *reinterpret_cast<short8*>(dst + 8) = o1;
    }
}

// =====================================================================
// quadratic SSD attention — one (i-tile, j-slice) per block.
// Plain stores into partial buffers; p1/p2 only written where meaningful.
// =====================================================================
__global__ __launch_bounds__(256) void attn_kernel(
    const __hip_bfloat16* __restrict__ q,   // [B,NH,L,HD]
    const __hip_bfloat16* __restrict__ k,   // [B,NH,L,HD]
    const __hip_bfloat16* __restrict__ vt,  // [B,NH,HD,L], dt-scaled
    const float* __restrict__ cs,           // [B,NH,L]
    float* __restrict__ p0,                 // [B,L,DSSM] partials
    float* __restrict__ p1,
    float* __restrict__ p2)
{
    const int pidx = blockIdx.x;            // 0..29
    const int it   = kIt[pidx];
    const int sl   = kS[pidx];
    const int nh   = blockIdx.y;
    const int b    = blockIdx.z;
    const int tid  = threadIdx.x;
    const int lane = tid & 63;
    const int wave = tid >> 6;
    const int col  = lane & 15;
    const int quad = lane >> 4;
    const int bnh  = b * NH_ + nh;
    const int iw0  = it * 64 + wave * 16;   // this wave's 16 i-rows

    float* pout = (sl == 0) ? p0 : ((sl == 1) ? p1 : p2);

    const short* qp  = reinterpret_cast<const short*>(q);
    const short* kp  = reinterpret_cast<const short*>(k);
    const short* vtp = reinterpret_cast<const short*>(vt);

    __shared__ alignas(16) short Ks[4096];        // [2][64][32] (HD halves)
    __shared__ alignas(16) short Ps[4 * 16 * 72]; // per-wave 16x72 P tile

    // Q fragments (A-layout)
    const short* qrow = qp + ((size_t)bnh * L_ + iw0 + col) * HD_;
    short8 aq0 = *reinterpret_cast<const short8*>(qrow + quad * 8);
    short8 aq1 = *reinterpret_cast<const short8*>(qrow + 32 + quad * 8);

    float csr[4];
#pragma unroll
    for (int r = 0; r < 4; ++r)
        csr[r] = cs[(size_t)bnh * L_ + iw0 + quad * 4 + r];

    floatx4 accO[4] = {};

    const int jt_end = min(sl * 6 + 5, it);
    for (int jt = sl * 6; jt <= jt_end; ++jt) {
        const int j0 = jt * 64;
        // stage K tile rows j0..j0+63
        {
            const short* gk = kp + ((size_t)bnh * L_ + j0 + wave * 16 + (lane >> 2)) * HD_
                            + (lane & 3) * 8;
            gload_lds16(gk,      &Ks[wave * 512 + lane * 8]);
            gload_lds16(gk + 32, &Ks[2048 + wave * 512 + lane * 8]);
        }
        __syncthreads();

        // ---- QK^T + decay -> Ps ----
#pragma unroll
        for (int s = 0; s < 4; ++s) {
            int jsub = j0 + s * 16;
            if (jsub <= iw0 + 15) {
                short8 bk0 = *reinterpret_cast<const short8*>(
                    &Ks[(s * 16 + col) * 32 + quad * 8]);
                short8 bk1 = *reinterpret_cast<const short8*>(
                    &Ks[2048 + (s * 16 + col) * 32 + quad * 8]);
                floatx4 sc = {};
                sc = __builtin_amdgcn_mfma_f32_16x16x32_bf16(aq0, bk0, sc, 0, 0, 0);
                sc = __builtin_amdgcn_mfma_f32_16x16x32_bf16(aq1, bk1, sc, 0, 0, 0);
                int j = jsub + col;
                float csj = cs[(size_t)bnh * L_ + j];
#pragma unroll
                for (int r = 0; r < 4; ++r) {
                    int i = iw0 + quad * 4 + r;
                    float e = (j <= i) ? __expf(csr[r] - csj) : 0.f;
                    Ps[wave * 1152 + (quad * 4 + r) * 72 + s * 16 + col] =
                        f2bfs(sc[r] * e);
                }
            } else if (j0 + (s >> 1) * 32 <= iw0 + 15) {
#pragma unroll
                for (int r = 0; r < 4; ++r)
                    Ps[wave * 1152 + (quad * 4 + r) * 72 + s * 16 + col] = 0;
            }
        }

        // ---- PV: accO += P @ Vt ----
#pragma unroll
        for (int c = 0; c < 2; ++c) {
            if (j0 + c * 32 > iw0 + 15) continue;
            short8 pa = *reinterpret_cast<const short8*>(
                &Ps[wave * 1152 + col * 72 + c * 32 + quad * 8]);
#pragma unroll
            for (int nt = 0; nt < 4; ++nt) {
                short8 bv = *reinterpret_cast<const short8*>(
                    vtp + ((size_t)bnh * HD_ + nt * 16 + col) * L_
                        + j0 + c * 32 + quad * 8);
                accO[nt] = __builtin_amdgcn_mfma_f32_16x16x32_bf16(pa, bv, accO[nt], 0, 0, 0);
            }
        }
        __syncthreads();
    }

    // ---- plain store into this slice's partial buffer ----
#pragma unroll
    for (int nt = 0; nt < 4; ++nt) {
#pragma unroll
        for (int r = 0; r < 4; ++r) {
            int i  = iw0 + quad * 4 + r;
            int dv = nt * 16 + col;
            pout[((size_t)b * L_ + i) * DSSM_ + nh * HD_ + dv] = accO[nt][r];
        }
    }
}

// =====================================================================
// gate: (p0[+p1][+p2] + v*D) * silu(z), then RMSNorm * rms_w  -> bf16
// p1 valid only for l>=384, p2 only for l>=768 (block-uniform branches)
// =====================================================================
__global__ __launch_bounds__(256) void gate_rms_kernel(
    const float* __restrict__ p0,
    const float* __restrict__ p1,
    const float* __restrict__ p2,
    const float* __restrict__ z,
    const __hip_bfloat16* __restrict__ v,   // [B,NH,L,HD]
    const float* __restrict__ Dm,           // [NH,HD]
    const float* __restrict__ rms_w,
    __hip_bfloat16* __restrict__ yn)
{
    int m   = blockIdx.x;           // b*L + l
    int b   = m / L_;
    int l   = m % L_;
    int tid = threadIdx.x;
    size_t base = (size_t)m * DSSM_;
    const bool has1 = (l >= 384);
    const bool has2 = (l >= 768);

    float g[6];
    float ss = 0.f;
#pragma unroll
    for (int t = 0; t < 6; ++t) {
        int c = tid + t * 256;
        int nh = c >> 6, d = c & 63;
        float vi = __bfloat162float(v[(((size_t)b * NH_ + nh) * L_ + l) * HD_ + d]);
        float yv = p0[base + c] + vi * Dm[c];
        if (has1) yv += p1[base + c];
        if (has2) yv += p2[base + c];
        float zv = fmaxf(z[base + c], -80.f);
        float gv = yv * (zv / (1.f + __expf(-zv)));
        g[t] = gv;
        ss += gv * gv;
    }
#pragma unroll
    for (int off = 32; off; off >>= 1) ss += __shfl_xor(ss, off, 64);
    __shared__ float red[4];
    if ((tid & 63) == 0) red[tid >> 6] = ss;
    __syncthreads();
    ss = red[0] + red[1] + red[2] + red[3];
    float r = rsqrtf(ss / (float)DSSM_ + 1e-6f);
#pragma unroll
    for (int t = 0; t < 6; ++t) {
        int c = tid + t * 256;
        yn[base + c] = __float2bfloat16(g[t] * r * rms_w[c]);
    }
}

// =====================================================================
extern "C" void kernel_launch(void* const* d_in, const int* in_sizes, int n_in,
                              void* d_out, int out_size, void* d_ws, size_t ws_size,
                              hipStream_t stream)
{
    const float* x       = (const float*)d_in[0];
    const float* w_qkv   = (const float*)d_in[1];
    const float* conv_w  = (const float*)d_in[2];
    const float* w_dt    = (const float*)d_in[3];
    const float* dt_bias = (const float*)d_in[4];
    const float* a_log   = (const float*)d_in[5];
    const float* Dm      = (const float*)d_in[6];
    const float* w_z     = (const float*)d_in[7];
    const float* b_z     = (const float*)d_in[8];
    const float* rms_w   = (const float*)d_in[9];
    const float* w_o     = (const float*)d_in[10];
    float* out = (float*)d_out;

    char* ws = (char*)d_ws;
    const int M = B_ * L_;                       // 2048

    // ---- workspace layout (bytes), total 80,805,888 ----
    __hip_bfloat16* xb    = (__hip_bfloat16*)(ws);                  // 0 .. 6.29M   (casts->step6)
    __hip_bfloat16* wqkvb = (__hip_bfloat16*)(ws + 6291456);        // 6.29 .. 20.45M (dead after step1)
    float*          p1    = (float*)(ws + 6291456);                 //   alias: partial 1
    __hip_bfloat16* wzb   = (__hip_bfloat16*)(ws + 20447232);       // -> step6
    __hip_bfloat16* wob   = (__hip_bfloat16*)(ws + 25165824);       // -> step8
    __hip_bfloat16* qkvb  = (__hip_bfloat16*)(ws + 29884416);       // 29.88 .. 48.76M (dead after step2)
    __hip_bfloat16* vtb   = (__hip_bfloat16*)(ws + 29884416);       //   alias: vt (transpose->attn)
    __hip_bfloat16* yn    = (__hip_bfloat16*)(ws + 29884416);       //   alias: yn (step7->8)
    float*          p2    = (float*)(ws + 36175872);                //   alias: partial 2 (after conv)
    __hip_bfloat16* qb    = (__hip_bfloat16*)(ws + 48758784);       // conv->attn
    __hip_bfloat16* kb    = (__hip_bfloat16*)(ws + 55050240);       // conv->attn
    float*          zbuf  = (float*)(ws + 48758784);                //   alias over qb+kb (step6->7)
    __hip_bfloat16* vb    = (__hip_bfloat16*)(ws + 61341696);       // conv->step7
    float* dt   = (float*)(ws + 67633152);
    float* dA   = (float*)(ws + 67829760);
    float* cs   = (float*)(ws + 68026368);
    float* p0   = (float*)(ws + 68222976);                          // partial 0 -> 80,805,888

    // 0) casts
    cast_kernel<<<(M * HID_) / 1024, 256, 0, stream>>>(x, xb, M * HID_);
    cast_kernel<<<(QKV_ * HID_) / 1024, 256, 0, stream>>>(w_qkv, wqkvb, QKV_ * HID_);
    cast_kernel<<<(DSSM_ * HID_) / 1024, 256, 0, stream>>>(w_z, wzb, DSSM_ * HID_);
    cast_kernel<<<(HID_ * DSSM_) / 1024, 256, 0, stream>>>(w_o, wob, HID_ * DSSM_);

    // 1) qkv = x @ w_qkv^T
    gemm_nt<2><<<dim3(QKV_ / 128, M / 128), 256, 0, stream>>>(
        xb, wqkvb, (void*)qkvb, nullptr, M, QKV_, HID_);

    // 2) conv + silu -> q,k,v
    conv_silu_kernel<<<(B_ * L_ * QKV_) / 256, 256, 0, stream>>>(
        qkvb, conv_w, qb, kb, vb);

    // 3) dt / dA  (LDS-staged, fp32)
    dtproj_kernel<<<M / 8, 256, 0, stream>>>(x, w_dt, dt_bias, a_log, dt, dA);

    // 4) cs = cumsum(dA)
    cumsum_kernel<<<B_ * NH_, 64, 0, stream>>>(dA, cs);

    // 5a) vt = transpose(v) * dt
    vdt_transpose_kernel<<<dim3(L_ / 64, NH_, B_), 256, 0, stream>>>(vb, dt, vtb);

    // 5b) attention: (i-tile, j-slice) blocks, plain stores into partials
    attn_kernel<<<dim3(30, NH_, B_), 256, 0, stream>>>(
        qb, kb, vtb, cs, p0, p1, p2);

    // 6) z = x @ w_z^T + b_z   (qb/kb dead; zbuf aliases them)
    gemm_nt<1><<<dim3(DSSM_ / 128, M / 128), 256, 0, stream>>>(
        xb, wzb, (void*)zbuf, b_z, M, DSSM_, HID_);

    // 7) gate (p0[+p1][+p2] + v*D) + RMSNorm -> yn (vt slot)
    gate_rms_kernel<<<M, 256, 0, stream>>>(p0, p1, p2, zbuf, vb, Dm, rms_w, yn);

    // 8) out = yn @ w_o^T
    gemm_nt<0><<<dim3(HID_ / 128, M / 128), 256, 0, stream>>>(
        yn, wob, (void*)out, nullptr, M, HID_, DSSM_);
}

// Round 10
// 340.558 us; speedup vs baseline: 1.2560x; 1.0850x over previous
//
#include <hip/hip_runtime.h>
#include <hip/hip_bf16.h>
#include <math.h>

// ---- problem constants ----
#define B_ 2
#define L_ 1024
#define HID_ 1536
#define NH_ 24
#define HD_ 64
#define DSSM_ 1536
#define QKV_ 4608
#define M_ 2048

typedef __attribute__((ext_vector_type(8))) short short8;
typedef __attribute__((ext_vector_type(4))) float floatx4;

// async global -> LDS, 16 bytes per lane (global_load_lds_dwordx4)
__device__ __forceinline__ void gload_lds16(const short* g, short* l)
{
    __builtin_amdgcn_global_load_lds(
        (const __attribute__((address_space(1))) void*)g,
        (__attribute__((address_space(3))) void*)l,
        16, 0, 0);
}

__device__ __forceinline__ float bfs2f(short s)
{
    unsigned u = ((unsigned)(unsigned short)s) << 16;
    float f; __builtin_memcpy(&f, &u, 4); return f;
}
__device__ __forceinline__ short f2bfs(float f)
{
    __hip_bfloat16 h = __float2bfloat16(f);
    short s; __builtin_memcpy(&s, &h, 2); return s;
}

// (it, slice) lookup for the 30 slice-blocks per (b,nh)
__device__ const int kIt[30] = {0,1,2,3,4,5, 6,6, 7,7, 8,8, 9,9, 10,10, 11,11,
                                12,12,12, 13,13,13, 14,14,14, 15,15,15};
__device__ const int kS[30]  = {0,0,0,0,0,0, 0,1, 0,1, 0,1, 0,1, 0,1, 0,1,
                                0,1,2, 0,1,2, 0,1,2, 0,1,2};

// =====================================================================
// fused fp32 -> bf16 cast for x, w_qkv, w_z (contiguous into wcat), w_o
// =====================================================================
#define CN0 (M_ * HID_)       // 3,145,728
#define CN1 (QKV_ * HID_)     // 7,077,888
#define CN2 (DSSM_ * HID_)    // 2,359,296
#define CN3 (HID_ * DSSM_)    // 2,359,296
__global__ void cast_all_kernel(
    const float* __restrict__ x,  const float* __restrict__ wq,
    const float* __restrict__ wz, const float* __restrict__ wo,
    __hip_bfloat16* __restrict__ xb,
    __hip_bfloat16* __restrict__ wcat,   // [QKV+DSSM, HID]
    __hip_bfloat16* __restrict__ wob)
{
    int i = (blockIdx.x * 256 + threadIdx.x) * 4;
    const float* src; __hip_bfloat16* dst; int off;
    if (i < CN0)                   { src = x;  dst = xb;         off = i; }
    else if (i < CN0 + CN1)        { src = wq; dst = wcat;       off = i - CN0; }
    else if (i < CN0 + CN1 + CN2)  { src = wz; dst = wcat + CN1; off = i - CN0 - CN1; }
    else                           { src = wo; dst = wob;        off = i - CN0 - CN1 - CN2; }
    float4 f = *reinterpret_cast<const float4*>(src + off);
    dst[off]     = __float2bfloat16(f.x);
    dst[off + 1] = __float2bfloat16(f.y);
    dst[off + 2] = __float2bfloat16(f.z);
    dst[off + 3] = __float2bfloat16(f.w);
}

// =====================================================================
// Fused qkv+z GEMM: C[M, 6144] = xb[M,K] @ wcat[6144,K]^T
// cols < QKV -> bf16 qkv_out; cols >= QKV -> fp32 + b_z -> z_out
// 768 blocks (48 x 16) = 3 blocks/CU exactly.
// =====================================================================
__global__ __launch_bounds__(256) void gemm_qkvz(
    const __hip_bfloat16* __restrict__ A,
    const __hip_bfloat16* __restrict__ Bm,
    __hip_bfloat16* __restrict__ qkv_out,
    float* __restrict__ z_out,
    const float* __restrict__ b_z)
{
    const int K = HID_;
    const int lane  = threadIdx.x & 63;
    const int wave  = threadIdx.x >> 6;
    const int col16 = lane & 15;
    const int quad  = lane >> 4;
    const int wr    = wave >> 1;
    const int wc    = wave & 1;
    const int rowblk = blockIdx.y * 128;
    const int colblk = blockIdx.x * 128;

    const short* Ap = reinterpret_cast<const short*>(A);
    const short* Bp = reinterpret_cast<const short*>(Bm);

    __shared__ alignas(16) short As[128 * 32];
    __shared__ alignas(16) short Bs[128 * 32];

    const int srow = lane >> 2;
    const int scol = (lane & 3) * 8;

    floatx4 acc[4][4] = {};

    for (int k0 = 0; k0 < K; k0 += 32) {
#pragma unroll
        for (int s2 = 0; s2 < 2; ++s2) {
            const int seg = wave * 2 + s2;
            gload_lds16(Ap + (size_t)(rowblk + seg * 16 + srow) * K + k0 + scol,
                        &As[seg * 512]);
            gload_lds16(Bp + (size_t)(colblk + seg * 16 + srow) * K + k0 + scol,
                        &Bs[seg * 512]);
        }
        __syncthreads();

        short8 af[4], bf[4];
#pragma unroll
        for (int t = 0; t < 4; ++t) {
            af[t] = *reinterpret_cast<const short8*>(
                &As[(wr * 64 + t * 16 + col16) * 32 + quad * 8]);
            bf[t] = *reinterpret_cast<const short8*>(
                &Bs[(wc * 64 + t * 16 + col16) * 32 + quad * 8]);
        }
#pragma unroll
        for (int mt = 0; mt < 4; ++mt)
#pragma unroll
            for (int nt = 0; nt < 4; ++nt)
                acc[mt][nt] = __builtin_amdgcn_mfma_f32_16x16x32_bf16(
                    af[mt], bf[nt], acc[mt][nt], 0, 0, 0);
        __syncthreads();
    }

    const int row0 = rowblk + wr * 64;
    const int col0 = colblk + wc * 64;
    if (colblk < QKV_) {
#pragma unroll
        for (int mt = 0; mt < 4; ++mt)
#pragma unroll
            for (int nt = 0; nt < 4; ++nt)
#pragma unroll
                for (int r = 0; r < 4; ++r) {
                    int row = row0 + mt * 16 + quad * 4 + r;
                    int col = col0 + nt * 16 + col16;
                    qkv_out[(size_t)row * QKV_ + col] = __float2bfloat16(acc[mt][nt][r]);
                }
    } else {
#pragma unroll
        for (int mt = 0; mt < 4; ++mt)
#pragma unroll
            for (int nt = 0; nt < 4; ++nt)
#pragma unroll
                for (int r = 0; r < 4; ++r) {
                    int row = row0 + mt * 16 + quad * 4 + r;
                    int col = col0 + nt * 16 + col16 - QKV_;
                    z_out[(size_t)row * DSSM_ + col] = acc[mt][nt][r] + b_z[col];
                }
    }
}

// =====================================================================
// NT GEMM, LDS-staged (m97 structure) — used for the output projection
// =====================================================================
template<int OUTMODE>
__global__ __launch_bounds__(256) void gemm_nt(
    const __hip_bfloat16* __restrict__ A,
    const __hip_bfloat16* __restrict__ Bm,
    void* __restrict__ Cv,
    const float* __restrict__ bias,
    int M, int N, int K)
{
    const int lane  = threadIdx.x & 63;
    const int wave  = threadIdx.x >> 6;
    const int col16 = lane & 15;
    const int quad  = lane >> 4;
    const int wr    = wave >> 1;
    const int wc    = wave & 1;
    const int rowblk = blockIdx.y * 128;
    const int colblk = blockIdx.x * 128;

    const short* Ap = reinterpret_cast<const short*>(A);
    const short* Bp = reinterpret_cast<const short*>(Bm);

    __shared__ alignas(16) short As[128 * 32];
    __shared__ alignas(16) short Bs[128 * 32];

    const int srow = lane >> 2;
    const int scol = (lane & 3) * 8;

    floatx4 acc[4][4] = {};

    for (int k0 = 0; k0 < K; k0 += 32) {
#pragma unroll
        for (int s2 = 0; s2 < 2; ++s2) {
            const int seg = wave * 2 + s2;
            gload_lds16(Ap + (size_t)(rowblk + seg * 16 + srow) * K + k0 + scol,
                        &As[seg * 512]);
            gload_lds16(Bp + (size_t)(colblk + seg * 16 + srow) * K + k0 + scol,
                        &Bs[seg * 512]);
        }
        __syncthreads();

        short8 af[4], bf[4];
#pragma unroll
        for (int t = 0; t < 4; ++t) {
            af[t] = *reinterpret_cast<const short8*>(
                &As[(wr * 64 + t * 16 + col16) * 32 + quad * 8]);
            bf[t] = *reinterpret_cast<const short8*>(
                &Bs[(wc * 64 + t * 16 + col16) * 32 + quad * 8]);
        }
#pragma unroll
        for (int mt = 0; mt < 4; ++mt)
#pragma unroll
            for (int nt = 0; nt < 4; ++nt)
                acc[mt][nt] = __builtin_amdgcn_mfma_f32_16x16x32_bf16(
                    af[mt], bf[nt], acc[mt][nt], 0, 0, 0);
        __syncthreads();
    }

    const int row0 = rowblk + wr * 64;
    const int col0 = colblk + wc * 64;
#pragma unroll
    for (int mt = 0; mt < 4; ++mt) {
#pragma unroll
        for (int nt = 0; nt < 4; ++nt) {
#pragma unroll
            for (int r = 0; r < 4; ++r) {
                int row = row0 + mt * 16 + quad * 4 + r;
                int col = col0 + nt * 16 + col16;
                float v = acc[mt][nt][r];
                if (OUTMODE == 1) v += bias[col];
                if (OUTMODE == 2)
                    ((__hip_bfloat16*)Cv)[(size_t)row * N + col] = __float2bfloat16(v);
                else
                    ((float*)Cv)[(size_t)row * N + col] = v;
            }
        }
    }
}

// =====================================================================
// depthwise causal conv (k=2) + SiLU -> q/k/v [B,NH,L,HD] bf16
// =====================================================================
__global__ void conv_silu_kernel(
    const __hip_bfloat16* __restrict__ raw,
    const float* __restrict__ conv_w,
    __hip_bfloat16* __restrict__ q,
    __hip_bfloat16* __restrict__ k,
    __hip_bfloat16* __restrict__ v)
{
    int idx = blockIdx.x * 256 + threadIdx.x;   // over B*L*QKV
    int c  = idx % QKV_;
    int ml = idx / QKV_;
    int l  = ml % L_;

    float cur  = __bfloat162float(raw[idx]);
    float prev = (l > 0) ? __bfloat162float(raw[idx - QKV_]) : 0.f;
    float u = prev * conv_w[c * 2] + cur * conv_w[c * 2 + 1];
    u = fmaxf(u, -80.f);
    float s = u / (1.f + __expf(-u));           // silu

    int part = c / DSSM_;
    int cc   = c % DSSM_;
    int nh   = cc >> 6;
    int d    = cc & 63;
    int b    = ml / L_;
    __hip_bfloat16* dst = (part == 0) ? q : ((part == 1) ? k : v);
    dst[(((size_t)b * NH_ + nh) * L_ + l) * HD_ + d] = __float2bfloat16(s);
}

// =====================================================================
// dt projection v2 (fp32, LDS-staged x, register-held fragments)
// =====================================================================
__global__ __launch_bounds__(256) void dtproj_kernel(
    const float* __restrict__ x,        // [B*L, HID]
    const float* __restrict__ w_dt,     // [NH, HID]
    const float* __restrict__ dt_bias,  // [NH]
    const float* __restrict__ a_log,    // [NH]
    float* __restrict__ dt,             // [B*NH, L]
    float* __restrict__ dA)
{
    const int m0   = blockIdx.x * 8;
    const int tid  = threadIdx.x;
    const int wave = tid >> 6;
    const int lane = tid & 63;

    __shared__ float Xs[8][HID_];

    for (int t = tid; t < 8 * (HID_ / 4); t += 256) {
        int r = t / (HID_ / 4), c = (t % (HID_ / 4)) * 4;
        *reinterpret_cast<float4*>(&Xs[r][c]) =
            *reinterpret_cast<const float4*>(x + (size_t)(m0 + r) * HID_ + c);
    }
    __syncthreads();

    const int r0 = wave * 2;
    float4 xa[2][6];
#pragma unroll
    for (int rr = 0; rr < 2; ++rr)
#pragma unroll
        for (int it = 0; it < 6; ++it)
            xa[rr][it] = *reinterpret_cast<const float4*>(&Xs[r0 + rr][lane * 4 + it * 256]);

    for (int n = 0; n < NH_; ++n) {
        float s0 = 0.f, s1 = 0.f;
#pragma unroll
        for (int it = 0; it < 6; ++it) {
            float4 w = *reinterpret_cast<const float4*>(
                w_dt + (size_t)n * HID_ + lane * 4 + it * 256);
            s0 += xa[0][it].x * w.x + xa[0][it].y * w.y
                + xa[0][it].z * w.z + xa[0][it].w * w.w;
            s1 += xa[1][it].x * w.x + xa[1][it].y * w.y
                + xa[1][it].z * w.z + xa[1][it].w * w.w;
        }
#pragma unroll
        for (int off = 32; off; off >>= 1) {
            s0 += __shfl_xor(s0, off, 64);
            s1 += __shfl_xor(s1, off, 64);
        }
        if (lane == 0) {
            float Aval = -__expf(a_log[n]);
            float bias = dt_bias[n];
#pragma unroll
            for (int rr = 0; rr < 2; ++rr) {
                float vdt = (rr == 0 ? s0 : s1) + bias;
                vdt = (vdt > 20.f) ? vdt : log1pf(__expf(vdt));
                int m = m0 + r0 + rr;
                int b = m / L_, l = m % L_;
                size_t o = ((size_t)b * NH_ + n) * L_ + l;
                dt[o] = vdt;
                dA[o] = vdt * Aval;
            }
        }
    }
}

// =====================================================================
// cumsum over L per (b,nh)
// =====================================================================
__global__ void cumsum_kernel(const float* __restrict__ dA, float* __restrict__ cs)
{
    int bnh  = blockIdx.x;
    int lane = threadIdx.x;
    const float* src = dA + (size_t)bnh * L_;
    float* dst       = cs + (size_t)bnh * L_;

    float loc[16];
    float run = 0.f;
#pragma unroll
    for (int t = 0; t < 16; ++t) { run += src[lane * 16 + t]; loc[t] = run; }
    float tot = run;
    float sc = tot;
#pragma unroll
    for (int off = 1; off < 64; off <<= 1) {
        float o = __shfl_up(sc, off, 64);
        if (lane >= off) sc += o;
    }
    float offset = sc - tot;
#pragma unroll
    for (int t = 0; t < 16; ++t) dst[lane * 16 + t] = loc[t] + offset;
}

// =====================================================================
// V -> Vt transpose with dt folding
// =====================================================================
__global__ __launch_bounds__(256) void vdt_transpose_kernel(
    const __hip_bfloat16* __restrict__ v,   // [B,NH,L,HD]
    const float* __restrict__ dt,           // [B,NH,L]
    __hip_bfloat16* __restrict__ vt)        // [B,NH,HD,L] (dt-scaled)
{
    const int lt0 = blockIdx.x * 64;
    const int bnh = blockIdx.z * NH_ + blockIdx.y;
    const int tid = threadIdx.x;

    __shared__ short T[64][72];

    {
        int row = tid >> 2;
        int cc  = (tid & 3) * 16;
        const short* sp = reinterpret_cast<const short*>(v)
                        + ((size_t)bnh * L_ + lt0 + row) * HD_ + cc;
        float dtr = dt[(size_t)bnh * L_ + lt0 + row];
        short8 a = *reinterpret_cast<const short8*>(sp);
        short8 b = *reinterpret_cast<const short8*>(sp + 8);
#pragma unroll
        for (int j = 0; j < 8; ++j) {
            T[row][cc + j]     = f2bfs(bfs2f(a[j]) * dtr);
            T[row][cc + 8 + j] = f2bfs(bfs2f(b[j]) * dtr);
        }
    }
    __syncthreads();
    {
        int d  = tid >> 2;
        int lc = (tid & 3) * 16;
        short8 o0, o1;
#pragma unroll
        for (int j = 0; j < 8; ++j) {
            o0[j] = T[lc + j][d];
            o1[j] = T[lc + 8 + j][d];
        }
        short* dst = reinterpret_cast<short*>(vt)
                   + ((size_t)bnh * HD_ + d) * L_ + lt0 + lc;
        *reinterpret_cast<short8*>(dst)     = o0;
        *reinterpret_cast<short8*>(dst + 8) = o1;
    }
}

// =====================================================================
// quadratic SSD attention — one (i-tile, j-slice) per block.
// =====================================================================
__global__ __launch_bounds__(256) void attn_kernel(
    const __hip_bfloat16* __restrict__ q,   // [B,NH,L,HD]
    const __hip_bfloat16* __restrict__ k,   // [B,NH,L,HD]
    const __hip_bfloat16* __restrict__ vt,  // [B,NH,HD,L], dt-scaled
    const float* __restrict__ cs,           // [B,NH,L]
    float* __restrict__ p0,                 // [B,L,DSSM] partials
    float* __restrict__ p1,
    float* __restrict__ p2)
{
    const int pidx = blockIdx.x;            // 0..29
    const int it   = kIt[pidx];
    const int sl   = kS[pidx];
    const int nh   = blockIdx.y;
    const int b    = blockIdx.z;
    const int tid  = threadIdx.x;
    const int lane = tid & 63;
    const int wave = tid >> 6;
    const int col  = lane & 15;
    const int quad = lane >> 4;
    const int bnh  = b * NH_ + nh;
    const int iw0  = it * 64 + wave * 16;

    float* pout = (sl == 0) ? p0 : ((sl == 1) ? p1 : p2);

    const short* qp  = reinterpret_cast<const short*>(q);
    const short* kp  = reinterpret_cast<const short*>(k);
    const short* vtp = reinterpret_cast<const short*>(vt);

    __shared__ alignas(16) short Ks[4096];
    __shared__ alignas(16) short Ps[4 * 16 * 72];

    const short* qrow = qp + ((size_t)bnh * L_ + iw0 + col) * HD_;
    short8 aq0 = *reinterpret_cast<const short8*>(qrow + quad * 8);
    short8 aq1 = *reinterpret_cast<const short8*>(qrow + 32 + quad * 8);

    float csr[4];
#pragma unroll
    for (int r = 0; r < 4; ++r)
        csr[r] = cs[(size_t)bnh * L_ + iw0 + quad * 4 + r];

    floatx4 accO[4] = {};

    const int jt_end = min(sl * 6 + 5, it);
    for (int jt = sl * 6; jt <= jt_end; ++jt) {
        const int j0 = jt * 64;
        {
            const short* gk = kp + ((size_t)bnh * L_ + j0 + wave * 16 + (lane >> 2)) * HD_
                            + (lane & 3) * 8;
            gload_lds16(gk,      &Ks[wave * 512 + lane * 8]);
            gload_lds16(gk + 32, &Ks[2048 + wave * 512 + lane * 8]);
        }
        __syncthreads();

#pragma unroll
        for (int s = 0; s < 4; ++s) {
            int jsub = j0 + s * 16;
            if (jsub <= iw0 + 15) {
                short8 bk0 = *reinterpret_cast<const short8*>(
                    &Ks[(s * 16 + col) * 32 + quad * 8]);
                short8 bk1 = *reinterpret_cast<const short8*>(
                    &Ks[2048 + (s * 16 + col) * 32 + quad * 8]);
                floatx4 sc = {};
                sc = __builtin_amdgcn_mfma_f32_16x16x32_bf16(aq0, bk0, sc, 0, 0, 0);
                sc = __builtin_amdgcn_mfma_f32_16x16x32_bf16(aq1, bk1, sc, 0, 0, 0);
                int j = jsub + col;
                float csj = cs[(size_t)bnh * L_ + j];
#pragma unroll
                for (int r = 0; r < 4; ++r) {
                    int i = iw0 + quad * 4 + r;
                    float e = (j <= i) ? __expf(csr[r] - csj) : 0.f;
                    Ps[wave * 1152 + (quad * 4 + r) * 72 + s * 16 + col] =
                        f2bfs(sc[r] * e);
                }
            } else if (j0 + (s >> 1) * 32 <= iw0 + 15) {
#pragma unroll
                for (int r = 0; r < 4; ++r)
                    Ps[wave * 1152 + (quad * 4 + r) * 72 + s * 16 + col] = 0;
            }
        }

#pragma unroll
        for (int c = 0; c < 2; ++c) {
            if (j0 + c * 32 > iw0 + 15) continue;
            short8 pa = *reinterpret_cast<const short8*>(
                &Ps[wave * 1152 + col * 72 + c * 32 + quad * 8]);
#pragma unroll
            for (int nt = 0; nt < 4; ++nt) {
                short8 bv = *reinterpret_cast<const short8*>(
                    vtp + ((size_t)bnh * HD_ + nt * 16 + col) * L_
                        + j0 + c * 32 + quad * 8);
                accO[nt] = __builtin_amdgcn_mfma_f32_16x16x32_bf16(pa, bv, accO[nt], 0, 0, 0);
            }
        }
        __syncthreads();
    }

#pragma unroll
    for (int nt = 0; nt < 4; ++nt) {
#pragma unroll
        for (int r = 0; r < 4; ++r) {
            int i  = iw0 + quad * 4 + r;
            int dv = nt * 16 + col;
            pout[((size_t)b * L_ + i) * DSSM_ + nh * HD_ + dv] = accO[nt][r];
        }
    }
}

// =====================================================================
// gate: (p0[+p1][+p2] + v*D) * silu(z), then RMSNorm * rms_w  -> bf16
// =====================================================================
__global__ __launch_bounds__(256) void gate_rms_kernel(
    const float* __restrict__ p0,
    const float* __restrict__ p1,
    const float* __restrict__ p2,
    const float* __restrict__ z,
    const __hip_bfloat16* __restrict__ v,   // [B,NH,L,HD]
    const float* __restrict__ Dm,           // [NH,HD]
    const float* __restrict__ rms_w,
    __hip_bfloat16* __restrict__ yn)
{
    int m   = blockIdx.x;           // b*L + l
    int b   = m / L_;
    int l   = m % L_;
    int tid = threadIdx.x;
    size_t base = (size_t)m * DSSM_;
    const bool has1 = (l >= 384);
    const bool has2 = (l >= 768);

    float g[6];
    float ss = 0.f;
#pragma unroll
    for (int t = 0; t < 6; ++t) {
        int c = tid + t * 256;
        int nh = c >> 6, d = c & 63;
        float vi = __bfloat162float(v[(((size_t)b * NH_ + nh) * L_ + l) * HD_ + d]);
        float yv = p0[base + c] + vi * Dm[c];
        if (has1) yv += p1[base + c];
        if (has2) yv += p2[base + c];
        float zv = fmaxf(z[base + c], -80.f);
        float gv = yv * (zv / (1.f + __expf(-zv)));
        g[t] = gv;
        ss += gv * gv;
    }
#pragma unroll
    for (int off = 32; off; off >>= 1) ss += __shfl_xor(ss, off, 64);
    __shared__ float red[4];
    if ((tid & 63) == 0) red[tid >> 6] = ss;
    __syncthreads();
    ss = red[0] + red[1] + red[2] + red[3];
    float r = rsqrtf(ss / (float)DSSM_ + 1e-6f);
#pragma unroll
    for (int t = 0; t < 6; ++t) {
        int c = tid + t * 256;
        yn[base + c] = __float2bfloat16(g[t] * r * rms_w[c]);
    }
}

// =====================================================================
extern "C" void kernel_launch(void* const* d_in, const int* in_sizes, int n_in,
                              void* d_out, int out_size, void* d_ws, size_t ws_size,
                              hipStream_t stream)
{
    const float* x       = (const float*)d_in[0];
    const float* w_qkv   = (const float*)d_in[1];
    const float* conv_w  = (const float*)d_in[2];
    const float* w_dt    = (const float*)d_in[3];
    const float* dt_bias = (const float*)d_in[4];
    const float* a_log   = (const float*)d_in[5];
    const float* Dm      = (const float*)d_in[6];
    const float* w_z     = (const float*)d_in[7];
    const float* b_z     = (const float*)d_in[8];
    const float* rms_w   = (const float*)d_in[9];
    const float* w_o     = (const float*)d_in[10];
    float* out = (float*)d_out;

    char* ws = (char*)d_ws;

    // ---- workspace layout (bytes), total 80,805,888 — overlap-audited ----
    // [0,         6291456)  : xb (cast->step1) -> vtb (5a->5b) -> yn (7->8)
    // [6291456,  11010048)  : wob (cast->step8, never reused)
    // [11010048, 23592960)  : zbuf fp32 (step1->step7)
    // [23592960, 61341696)  : wcat [23592960,42467328) + qkvb [42467328,61341696)
    //                         -> after step2 both dead -> p0|p1|p2 (3 x 12582912)
    // [61341696, 67633152)  : qb (step2->5b)
    // [67633152, 73924608)  : kb (step2->5b)
    // [73924608, 80216064)  : vb (step2->7)
    // [80216064, 80805888)  : dt | dA | cs
    __hip_bfloat16* xb    = (__hip_bfloat16*)(ws);
    __hip_bfloat16* wob   = (__hip_bfloat16*)(ws + 6291456);
    float*          zbuf  = (float*)(ws + 11010048);
    __hip_bfloat16* wcat  = (__hip_bfloat16*)(ws + 23592960);
    __hip_bfloat16* qkvb  = (__hip_bfloat16*)(ws + 42467328);
    __hip_bfloat16* qb    = (__hip_bfloat16*)(ws + 61341696);
    __hip_bfloat16* kb    = (__hip_bfloat16*)(ws + 67633152);
    __hip_bfloat16* vb    = (__hip_bfloat16*)(ws + 73924608);
    float* dt   = (float*)(ws + 80216064);
    float* dA   = (float*)(ws + 80412672);
    float* cs   = (float*)(ws + 80609280);
    // aliases (lifetimes disjoint per audit above)
    __hip_bfloat16* vtb = (__hip_bfloat16*)(ws);
    __hip_bfloat16* yn  = (__hip_bfloat16*)(ws);
    float* p0 = (float*)(ws + 23592960);
    float* p1 = (float*)(ws + 36175872);
    float* p2 = (float*)(ws + 48758784);

    // 0) fused casts: x->xb, w_qkv|w_z->wcat, w_o->wob
    cast_all_kernel<<<(CN0 + CN1 + CN2 + CN3) / 1024, 256, 0, stream>>>(
        x, w_qkv, w_z, w_o, xb, wcat, wob);

    // 1) fused qkv+z GEMM  [2048 x 6144]
    gemm_qkvz<<<dim3((QKV_ + DSSM_) / 128, M_ / 128), 256, 0, stream>>>(
        xb, wcat, qkvb, zbuf, b_z);

    // 2) conv + silu -> q,k,v
    conv_silu_kernel<<<(B_ * L_ * QKV_) / 256, 256, 0, stream>>>(
        qkvb, conv_w, qb, kb, vb);

    // 3) dt / dA
    dtproj_kernel<<<M_ / 8, 256, 0, stream>>>(x, w_dt, dt_bias, a_log, dt, dA);

    // 4) cs = cumsum(dA)
    cumsum_kernel<<<B_ * NH_, 64, 0, stream>>>(dA, cs);

    // 5a) vt = transpose(v) * dt  (xb dead after step 1)
    vdt_transpose_kernel<<<dim3(L_ / 64, NH_, B_), 256, 0, stream>>>(vb, dt, vtb);

    // 5b) attention -> partials p0/p1/p2 (wcat+qkvb region dead)
    attn_kernel<<<dim3(30, NH_, B_), 256, 0, stream>>>(
        qb, kb, vtb, cs, p0, p1, p2);

    // 7) gate + RMSNorm -> yn (vtb slot; attn done)
    gate_rms_kernel<<<M_, 256, 0, stream>>>(p0, p1, p2, zbuf, vb, Dm, rms_w, yn);

    // 8) out = yn @ w_o^T
    gemm_nt<0><<<dim3(HID_ / 128, M_ / 128), 256, 0, stream>>>(
        yn, wob, (void*)out, nullptr, M_, HID_, DSSM_);
}